// Round 1
// baseline (104.673 us; speedup 1.0000x reference)
//
#include <hip/hip_runtime.h>
#include <hip/hip_bf16.h>

// Depthwise 1D conv, VALID, K=3.
// x:   (B=8, C=1024, N=8192) f32
// f:   (C=1024, K=3) f32
// out: (B=8, C=1024, N_out=8190) f32
//
// out[b,c,n] = x[n]*f0 + x[n+1]*f1 + x[n+2]*f2
//
// Memory-bound: ~512 MiB total traffic -> target ~85us at 6.3 TB/s.

#define C_DIM 1024
#define N_IN 8192
#define N_OUT 8190

__global__ __launch_bounds__(256) void dwconv1d_k3_kernel(
    const float* __restrict__ x,
    const float* __restrict__ filt,
    float* __restrict__ out)
{
    const int row = blockIdx.x;          // row = b*C + c, 8192 rows total
    const int c = row & (C_DIM - 1);     // C = 1024 (power of 2)

    // 3 taps, wave-uniform broadcast (same address across all lanes).
    const float f0 = filt[c * 3 + 0];
    const float f1 = filt[c * 3 + 1];
    const float f2 = filt[c * 3 + 2];

    const float* __restrict__ xr = x + (size_t)row * N_IN;   // 16B-aligned base
    float* __restrict__ orow = out + (size_t)row * N_OUT;    // 8B-aligned base

    // 2048 groups of 4 outputs; group 2047 has only 2 valid outputs
    // (n=8188,8189), which still read only in-bounds x[8188..8191].
    for (int g = threadIdx.x; g < 2048; g += 256) {
        const int n = g * 4;
        const float4 a = *reinterpret_cast<const float4*>(xr + n);  // 16B aligned
        if (g < 2047) {
            const float2 b = *reinterpret_cast<const float2*>(xr + n + 4);  // halo
            float2 lo, hi;
            lo.x = a.x * f0 + a.y * f1 + a.z * f2;
            lo.y = a.y * f0 + a.z * f1 + a.w * f2;
            hi.x = a.z * f0 + a.w * f1 + b.x * f2;
            hi.y = a.w * f0 + b.x * f1 + b.y * f2;
            *reinterpret_cast<float2*>(orow + n)     = lo;  // 8B aligned
            *reinterpret_cast<float2*>(orow + n + 2) = hi;
        } else {
            float2 lo;
            lo.x = a.x * f0 + a.y * f1 + a.z * f2;
            lo.y = a.y * f0 + a.z * f1 + a.w * f2;
            *reinterpret_cast<float2*>(orow + n) = lo;
        }
    }
}

extern "C" void kernel_launch(void* const* d_in, const int* in_sizes, int n_in,
                              void* d_out, int out_size, void* d_ws, size_t ws_size,
                              hipStream_t stream) {
    const float* x    = (const float*)d_in[0];
    const float* filt = (const float*)d_in[1];
    float* out        = (float*)d_out;

    const int rows = 8 * C_DIM;  // B * C = 8192
    dwconv1d_k3_kernel<<<rows, 256, 0, stream>>>(x, filt, out);
}